// Round 6
// baseline (132.744 us; speedup 1.0000x reference)
//
#include <hip/hip_runtime.h>
#include <cstdint>

#define BDIM  2
#define TSEQ  2048
#define CDIM  1024
#define NHEAD 16
#define HDIM  64
#define C3    3072

typedef __attribute__((ext_vector_type(8))) short short8_t;
typedef __attribute__((ext_vector_type(4))) float f32x4;

static __device__ __forceinline__ unsigned short f2bf(float f) {
  union { float f; unsigned u; } v; v.f = f;
  unsigned r = v.u + 0x7FFFu + ((v.u >> 16) & 1u);   // RNE
  return (unsigned short)(r >> 16);
}
// pack 2 f32 -> 2 bf16 in one u32 (v_cvt_pk_bf16_f32, RNE)
static __device__ __forceinline__ unsigned cvtpk_bf16(float lo, float hi) {
  unsigned r;
  asm("v_cvt_pk_bf16_f32 %0, %1, %2" : "=v"(r) : "v"(lo), "v"(hi));
  return r;
}
// async global->LDS, 16B per lane. LDS dest = wave-uniform base + lane*16.
static __device__ __forceinline__ void g2lds16(const unsigned short* g,
                                               unsigned short* l) {
  __builtin_amdgcn_global_load_lds(
      (const __attribute__((address_space(1))) void*)g,
      (__attribute__((address_space(3))) void*)l, 16, 0, 0);
}

// [rows][64] bf16 tiles, 16B chunks 0..7 (chunk=elem>>3), chunk ^= row&7.
// Used by GEMM A/B tiles (BK=64) and attn K tiles.
__device__ __forceinline__ int kk_idx(int row, int chunk) {
  return row * 64 + (((chunk ^ (row & 7)) & 7) << 3);
}
// attn V^T tile: [64 d][64 kv] bf16, chunks 0..7 (kv>>3),
// chunk ^= (d&7) ^ ((d>>3)&7)
__device__ __forceinline__ int vv_idx(int d, int chunk) {
  return d * 64 + (((chunk ^ (d & 7) ^ ((d >> 3) & 7)) & 7) << 3);
}

// ---------------------------------------------------------------------------
__global__ __launch_bounds__(256) void f32_to_bf16(
    const float* __restrict__ in, unsigned short* __restrict__ out, int n4)
{
  const int i = blockIdx.x * 256 + threadIdx.x;
  if (i < n4) {
    const float4 v = ((const float4*)in)[i];
    const unsigned lo = (unsigned)f2bf(v.x) | ((unsigned)f2bf(v.y) << 16);
    const unsigned hi = (unsigned)f2bf(v.z) | ((unsigned)f2bf(v.w) << 16);
    ((uint2*)out)[i] = make_uint2(lo, hi);
  }
}

// ---------------------------------------------------------------------------
// C[m][n] = sum_k A[m][k]*B[n][k] + bias[n]; A,B bf16, bias fp32.
// bf16 MFMA 16x16x32, 128x128 tile, BK=64, 4 waves, 4x4 frags/wave.
// Staging via global_load_lds (linear LDS dest, pre-swizzled global source):
// call c, lane tid: element = c*2048 + tid*8 -> row = c*32 + (tid>>3),
// c_lds = tid&7; source holds global chunk c_lds ^ (row&7).
// ---------------------------------------------------------------------------
template <bool OUT_BF16>
__global__ __launch_bounds__(256, 2) void gemm_bt_mfma(
    const unsigned short* __restrict__ A, const unsigned short* __restrict__ B,
    const float* __restrict__ bias, void* __restrict__ Cv,
    int M, int N, int K)
{
  __shared__ unsigned short As[128 * 64];
  __shared__ unsigned short Bs[128 * 64];

  const int tid  = threadIdx.x;
  const int lane = tid & 63;
  const int wv   = tid >> 6;
  const int wr   = wv >> 1, wc = wv & 1;
  const int l15  = lane & 15, g = lane >> 4;
  const int bn = blockIdx.x, bm = blockIdx.y;

  // staging source (pre-swizzled): row base tid>>3, global chunk
  const int srow = tid >> 3;                      // 0..31 (call adds c*32)
  const int chg  = (tid & 7) ^ (srow & 7);        // c*32 ≡ 0 (mod 8)
  const unsigned short* Ab = A + (size_t)(bm * 128 + srow) * K + chg * 8;
  const unsigned short* Bb = B + (size_t)(bn * 128 + srow) * K + chg * 8;

  f32x4 acc[4][4];
#pragma unroll
  for (int i = 0; i < 4; ++i)
#pragma unroll
    for (int j = 0; j < 4; ++j) acc[i][j] = (f32x4){0.f, 0.f, 0.f, 0.f};

  for (int k0 = 0; k0 < K; k0 += 64) {
    __syncthreads();            // prev iter's readers done
#pragma unroll
    for (int c = 0; c < 4; ++c) {
      g2lds16(Ab + (size_t)(c * 32) * K + k0, &As[c * 2048 + wv * 512]);
      g2lds16(Bb + (size_t)(c * 32) * K + k0, &Bs[c * 2048 + wv * 512]);
    }
    __syncthreads();            // implicit vmcnt(0) drains the DMA

#pragma unroll
    for (int kk = 0; kk < 2; ++kk) {
      short8_t af[4], bf[4];
#pragma unroll
      for (int i = 0; i < 4; ++i)
        af[i] = *(const short8_t*)&As[kk_idx(wr * 64 + i * 16 + l15, kk * 4 + g)];
#pragma unroll
      for (int j = 0; j < 4; ++j)
        bf[j] = *(const short8_t*)&Bs[kk_idx(wc * 64 + j * 16 + l15, kk * 4 + g)];
#pragma unroll
      for (int i = 0; i < 4; ++i)
#pragma unroll
        for (int j = 0; j < 4; ++j)
          acc[i][j] = __builtin_amdgcn_mfma_f32_16x16x32_bf16(af[i], bf[j], acc[i][j], 0, 0, 0);
    }
  }

#pragma unroll
  for (int j = 0; j < 4; ++j) {
    const int col = bn * 128 + wc * 64 + j * 16 + l15;
    const float bj = bias[col];
#pragma unroll
    for (int i = 0; i < 4; ++i) {
#pragma unroll
      for (int r = 0; r < 4; ++r) {
        const int row = bm * 128 + wr * 64 + i * 16 + g * 4 + r;
        const float v = acc[i][j][r] + bj;
        if (OUT_BF16) ((unsigned short*)Cv)[(size_t)row * N + col] = f2bf(v);
        else          ((float*)Cv)[(size_t)row * N + col] = v;
      }
    }
  }
}

// ---------------------------------------------------------------------------
// Causal flash attention, bf16 MFMA 16x16x32, SWAPPED QK^T (S^T = K·Q^T):
// lane-local softmax; packed b64 P writes via cvt_pk; K staged by
// global_load_lds direct into double-buffered LDS (DMA for tile t+1 issued
// right after tile t's barrier); V reg-staged transposed.
// Block = 4 waves; does q-tiles x and 31-x (33 KV tiles, balanced).
// grid: (16, NHEAD, BDIM).
// ---------------------------------------------------------------------------
__global__ __launch_bounds__(256, 2) void attn_mfma(
    const unsigned short* __restrict__ qkv, unsigned short* __restrict__ yb)
{
  __shared__ unsigned short Ks[2 * 64 * 64];
  __shared__ unsigned short Vt[2 * 64 * 64];
  __shared__ unsigned short Ps[4 * 16 * 72];

  const int tid  = threadIdx.x;
  const int lane = tid & 63;
  const int wv   = tid >> 6;
  const int l15  = lane & 15, g = lane >> 4;
  const int x = blockIdx.x, h = blockIdx.y, b = blockIdx.z;

  const unsigned short* kbase = qkv + (size_t)(b * TSEQ) * C3 + CDIM + h * HDIM;
  const unsigned short* vbase = kbase + CDIM;
  unsigned short* Pw = &Ps[wv * 16 * 72];

  const float SC2 = 0.18033688011112042f;   // log2(e)/8
  const float THR = 11.5415603f;            // 8*log2(e)

  // K DMA source (pre-swizzled): row tid>>3 (+32 for call 1), chunk chgK
  const int sK   = tid >> 3;
  const int chgK = (tid & 7) ^ (sK & 7);
  const unsigned short* kd0 = kbase + (size_t)sK * C3 + chgK * 8;
  // V reg-staging: rows 2*vs, 2*vs+1, d-chunk va; packed b32 writes
  const int vs = tid >> 3;            // 0..31 (kv pair)
  const int va = tid & 7;             // 0..7  (d chunk)
  int vwo[8];
#pragma unroll
  for (int j = 0; j < 8; ++j)
    vwo[j] = vv_idx(va * 8 + j, vs >> 2) + ((2 * vs) & 7);

  int tg = 0;   // staged-tile parity, continuous across phases

  for (int ph = 0; ph < 2; ++ph) {
    const int qt   = ph ? (31 - x) : x;
    const int wq0  = qt * 64 + wv * 16;
    const int q_hi = wq0 + 15;
    const int qg   = wq0 + l15;         // this lane's q row
    const int ntiles = qt + 1;

    // Q fragment (B-operand: col=q=l15, k=g*8+j)
    short8_t qf[2];
#pragma unroll
    for (int kk = 0; kk < 2; ++kk)
      qf[kk] = *(const short8_t*)(qkv +
          (size_t)(b * TSEQ + wq0 + l15) * C3 + h * HDIM + kk * 32 + g * 8);

    f32x4 O[4];
#pragma unroll
    for (int n = 0; n < 4; ++n) O[n] = (f32x4){0.f, 0.f, 0.f, 0.f};
    float Mr = -3.0e38f, Lr = 0.f;      // per-lane (q = l15)

    // prologue: DMA K(0) into current parity; V(0) into regs
    {
      unsigned short* Kb = &Ks[(tg & 1) * 4096];
      g2lds16(kd0, &Kb[wv * 512]);
      g2lds16(kd0 + (size_t)32 * C3, &Kb[2048 + wv * 512]);
    }
    const unsigned short* vptr0 = vbase + (size_t)(2 * vs) * C3 + va * 8;
    const unsigned short* vptr1 = vptr0 + C3;
    short8_t pv0 = *(const short8_t*)(vptr0);
    short8_t pv1 = *(const short8_t*)(vptr1);

    for (int t = 0; t < ntiles; ++t) {
      const int par = tg & 1;
      unsigned short* Kc = &Ks[par * 4096];
      unsigned short* Vc = &Vt[par * 4096];
      tg++;
      {
        const unsigned short* e0 = (const unsigned short*)&pv0;
        const unsigned short* e1 = (const unsigned short*)&pv1;
#pragma unroll
        for (int j = 0; j < 8; ++j)
          *(unsigned*)&Vc[vwo[j]] = (unsigned)e0[j] | ((unsigned)e1[j] << 16);
      }
      __syncthreads();          // drains K DMA + makes V writes visible
      if (t + 1 < ntiles) {     // issue next tile's K DMA + V reg loads
        unsigned short* Kn = &Ks[(par ^ 1) * 4096];
        const unsigned short* kn = kd0 + (size_t)(t + 1) * 64 * C3;
        g2lds16(kn, &Kn[wv * 512]);
        g2lds16(kn + (size_t)32 * C3, &Kn[2048 + wv * 512]);
        vptr0 += (size_t)64 * C3;
        vptr1 += (size_t)64 * C3;
        pv0 = *(const short8_t*)(vptr0);
        pv1 = *(const short8_t*)(vptr1);
      }
      const int kv0  = t * 64;
      const int nlim = (q_hi - kv0) >> 4;   // highest frag with unmasked cols

      // S^T = K Q^T  (D-layout: row(kv)=g*4+r, col(q)=l15)
      f32x4 s[4];
#pragma unroll
      for (int n = 0; n < 4; ++n) s[n] = (f32x4){0.f, 0.f, 0.f, 0.f};
#pragma unroll
      for (int n = 0; n < 4; ++n) {
        if (n <= nlim) {
#pragma unroll
          for (int kk = 0; kk < 2; ++kk) {
            const short8_t kf = *(const short8_t*)&Kc[kk_idx(n * 16 + l15, kk * 4 + g)];
            s[n] = __builtin_amdgcn_mfma_f32_16x16x32_bf16(kf, qf[kk], s[n], 0, 0, 0);
          }
        }
      }

      // scale (log2 domain) + causal mask + lane-local max
      float mt = -3.0e38f;
#pragma unroll
      for (int n = 0; n < 4; ++n) {
        if (n <= nlim) {
          const int kvb = kv0 + n * 16 + g * 4;
          const bool needmask = (kv0 + n * 16 + 15 > wq0);
#pragma unroll
          for (int r = 0; r < 4; ++r) {
            float v = s[n][r] * SC2;
            if (needmask && (kvb + r > qg)) v = -3.0e38f;
            s[n][r] = v;
            mt = fmaxf(mt, v);
          }
        }
      }
      mt = fmaxf(mt, __shfl_xor(mt, 16));
      mt = fmaxf(mt, __shfl_xor(mt, 32));

      if (__any(mt > Mr + THR)) {           // defer-max rescale
        const float nm = fmaxf(Mr, mt);
        const float al = __builtin_amdgcn_exp2f(Mr - nm);
        Lr *= al;
        Mr = nm;
        float alq[4];
#pragma unroll
        for (int r = 0; r < 4; ++r) alq[r] = __shfl(al, (g << 2) + r);
#pragma unroll
        for (int n = 0; n < 4; ++n)
#pragma unroll
          for (int r = 0; r < 4; ++r) O[n][r] *= alq[r];
      }

      float rs = 0.f;
#pragma unroll
      for (int n = 0; n < 4; ++n) {
        if (n <= nlim) {
#pragma unroll
          for (int r = 0; r < 4; ++r) {
            const float p = __builtin_amdgcn_exp2f(s[n][r] - Mr);
            s[n][r] = p;
            rs += p;
          }
        }
        // n > nlim: s[n] stays 0 -> zero P columns (PV-safe)
      }
      rs += __shfl_xor(rs, 16);
      rs += __shfl_xor(rs, 32);
      Lr += rs;

      // packed P write: row q=l15, cols kv = n*16 + g*4 .. +3 (b64 each)
#pragma unroll
      for (int n = 0; n < 4; ++n) {
        const unsigned u0 = cvtpk_bf16(s[n][0], s[n][1]);
        const unsigned u1 = cvtpk_bf16(s[n][2], s[n][3]);
        *(uint2*)&Pw[l15 * 72 + n * 16 + (g << 2)] = make_uint2(u0, u1);
      }

      // PV: A = P (row=q=l15, k=kk*32+g*8+j), B = V^T (col(d)=l15)
#pragma unroll
      for (int kk = 0; kk < 2; ++kk) {
        const short8_t pf = *(const short8_t*)&Pw[l15 * 72 + kk * 32 + g * 8];
#pragma unroll
        for (int n = 0; n < 4; ++n) {
          const short8_t vf = *(const short8_t*)&Vc[vv_idx(n * 16 + l15, kk * 4 + g)];
          O[n] = __builtin_amdgcn_mfma_f32_16x16x32_bf16(pf, vf, O[n], 0, 0, 0);
        }
      }
    }

    // epilogue: O rows are q = g*4+r; stats live at lane l15=q
    const float inv = 1.0f / Lr;
    float invq[4];
#pragma unroll
    for (int r = 0; r < 4; ++r) invq[r] = __shfl(inv, (g << 2) + r);
#pragma unroll
    for (int n = 0; n < 4; ++n)
#pragma unroll
      for (int r = 0; r < 4; ++r) {
        const size_t row = (size_t)(b * TSEQ + wq0 + (g << 2) + r);
        yb[row * CDIM + h * HDIM + n * 16 + l15] = f2bf(O[n][r] * invq[r]);
      }
  }
}

// ---------------------------------------------------------------------------
extern "C" void kernel_launch(void* const* d_in, const int* in_sizes, int n_in,
                              void* d_out, int out_size, void* d_ws, size_t ws_size,
                              hipStream_t stream)
{
  const float* x     = (const float*)d_in[0];   // [B,T,C] fp32
  const float* Wqkv  = (const float*)d_in[1];   // [3C,C]  fp32
  const float* bqkv  = (const float*)d_in[2];   // [3C]
  const float* Wproj = (const float*)d_in[3];   // [C,C]
  const float* bproj = (const float*)d_in[4];   // [C]
  float* out = (float*)d_out;                   // [B,T,C] fp32

  const int M = BDIM * TSEQ;                    // 4096
  unsigned short* qkv = (unsigned short*)d_ws;          // M x 3C
  unsigned short* yb  = qkv + (size_t)M * C3;           // M x C
  unsigned short* xb  = yb  + (size_t)M * CDIM;         // M x C
  unsigned short* wqb = xb  + (size_t)M * CDIM;         // 3C x C
  unsigned short* wpb = wqb + (size_t)C3 * CDIM;        // C x C

  // 0) fp32 -> bf16 pre-conversion (RNE)
  f32_to_bf16<<<(M * CDIM / 4 + 255) / 256, 256, 0, stream>>>(x, xb, M * CDIM / 4);
  f32_to_bf16<<<(C3 * CDIM / 4 + 255) / 256, 256, 0, stream>>>(Wqkv, wqb, C3 * CDIM / 4);
  f32_to_bf16<<<(CDIM * CDIM / 4 + 255) / 256, 256, 0, stream>>>(Wproj, wpb, CDIM * CDIM / 4);

  // 1) qkv = bf16(x @ Wqkv^T + bqkv)
  gemm_bt_mfma<true><<<dim3(C3 / 128, M / 128), 256, 0, stream>>>(
      xb, wqb, bqkv, (void*)qkv, M, C3, CDIM);

  // 2) causal attention -> yb (bf16)
  attn_mfma<<<dim3(16, NHEAD, BDIM), 256, 0, stream>>>(qkv, yb);

  // 3) out = yb @ Wproj^T + bproj (fp32 out)
  gemm_bt_mfma<false><<<dim3(CDIM / 128, M / 128), 256, 0, stream>>>(
      yb, wpb, bproj, (void*)out, M, CDIM, CDIM);
}